// Round 9
// baseline (169.336 us; speedup 1.0000x reference)
//
#include <hip/hip_runtime.h>
#include <hip/hip_bf16.h>
#include <stdint.h>

#define DM 1024
#define HD 128
#define NH 8
#define NB 2
#define TGT 1024
#define SRC 8192
#define JPH 1024
#define LOG2E 1.4426950408889634f

typedef __attribute__((ext_vector_type(8))) short bf16x8;
typedef __attribute__((ext_vector_type(4))) float f32x4;

__device__ __forceinline__ unsigned short f2bf(float f) {
  __hip_bfloat16 h = __float2bfloat16(f);
  return __builtin_bit_cast(unsigned short, h);
}

__device__ __forceinline__ void gload_lds16(const void* g, void* l) {
  __builtin_amdgcn_global_load_lds(
      (const __attribute__((address_space(1))) unsigned int*)g,
      (__attribute__((address_space(3))) unsigned int*)l, 16, 0, 0);
}

// ---------------------------------------------------------------------------
// Weight transpose + fp32->bf16 convert: WT[n][k] = bf16(W[k][n])
// ---------------------------------------------------------------------------
__global__ __launch_bounds__(256) void wconv_kernel(
    const float* __restrict__ Wq, const float* __restrict__ Wk,
    const float* __restrict__ Wv, const float* __restrict__ Wo,
    unsigned short* __restrict__ WTout) {
  __shared__ float tile[64][65];
  const float* W = (blockIdx.z == 0) ? Wq : (blockIdx.z == 1) ? Wk
                   : (blockIdx.z == 2) ? Wv : Wo;
  unsigned short* WT = WTout + (size_t)blockIdx.z * DM * DM;
  const int k0 = blockIdx.x * 64, n0 = blockIdx.y * 64;
  const int tid = threadIdx.x;
  const int tr = tid >> 4, tc = (tid & 15) * 4;
  for (int it = 0; it < 4; ++it) {
    int r = tr + it * 16;
    float4 vv = *(const float4*)(&W[(size_t)(k0 + r) * DM + n0 + tc]);
    tile[r][tc] = vv.x; tile[r][tc + 1] = vv.y;
    tile[r][tc + 2] = vv.z; tile[r][tc + 3] = vv.w;
  }
  __syncthreads();
  for (int it = 0; it < 4; ++it) {
    int n = tr + it * 16;
    ushort4 o;
    o.x = f2bf(tile[tc + 0][n]); o.y = f2bf(tile[tc + 1][n]);
    o.z = f2bf(tile[tc + 2][n]); o.w = f2bf(tile[tc + 3][n]);
    *(ushort4*)(&WT[(size_t)(n0 + n) * DM + k0 + tc]) = o;
  }
}

// ---------------------------------------------------------------------------
// Fused projection GEMM v7: BARRIER-FREE, LDS-FREE. Each wave independently
// computes a 32x64 output tile, loading A (fp32) and B (bf16 W^T) fragments
// directly global->registers. No s_barrier, no LDS, no vmcnt choreography ->
// compiler freely software-pipelines the fully-unrolled K loop (free-running
// m13 regime). B is duplicated across waves but L2-hot (XCD swizzle).
// Block = 4 waves stacked in M: BM=128, BN=64, grid 768 (8x96 XCD-swizzled).
//   lbid 0..255  : mode 0, Q -> Qp (scaled); Mtile=sub>>4, nbase=(sub&15)*64
//   lbid 256..511: mode 1, K rows j=h+8j' -> Kp
//   lbid 512..767: mode 2, V rows j=h+8j' -> VpT
//     (modes 1/2: bh=sub>>4, r=sub&15, Mtile=r>>1, nbase=(bh&7)*128+(r&1)*64)
// ---------------------------------------------------------------------------
__global__ __launch_bounds__(256, 3) void proj_fused_kernel(
    const float* __restrict__ q, const float* __restrict__ k,
    const float* __restrict__ v, const unsigned short* __restrict__ WTall,
    const float* __restrict__ bq, const float* __restrict__ bk,
    const float* __restrict__ bv, unsigned short* __restrict__ Qp,
    unsigned short* __restrict__ Kp, unsigned short* __restrict__ VpT) {
  const int tid = threadIdx.x, lane = tid & 63, w = tid >> 6;  // w = M-wave
  const int l15 = lane & 15, l4 = lane >> 4;

  // bijective XCD swizzle: 768 = 8 * 96
  const int bid = blockIdx.x;
  const int lbid = (bid & 7) * 96 + (bid >> 3);
  const int mode = lbid >> 8;
  const int sub = lbid & 255;
  const float* Asrc;
  const unsigned short* WT;
  const float* bias;
  int nbase, bh = 0, Mtile;
  if (mode == 0) {
    Asrc = q; WT = WTall; bias = bq;
    Mtile = sub >> 4; nbase = (sub & 15) * 64;
  } else {
    bh = sub >> 4;
    const int r = sub & 15;
    Mtile = r >> 1;
    nbase = (bh & 7) * 128 + (r & 1) * 64;
    if (mode == 1) { Asrc = k; WT = WTall + (size_t)DM * DM; bias = bk; }
    else           { Asrc = v; WT = WTall + (size_t)2 * DM * DM; bias = bv; }
  }

  // per-lane A row pointers (f = 0,1)
  const int mrow = Mtile * 128 + w * 32 + l15;   // + f*16
  const float* aA[2];
  if (mode == 0) {
    aA[0] = Asrc + (size_t)mrow * DM;
    aA[1] = Asrc + (size_t)(mrow + 16) * DM;
  } else {
    const size_t base = (size_t)(bh >> 3) * SRC + (size_t)(bh & 7);
    aA[0] = Asrc + (base + 8u * (size_t)mrow) * DM;
    aA[1] = Asrc + (base + 8u * (size_t)(mrow + 16)) * DM;
  }
  // per-lane B row pointers (g = 0..3)
  const unsigned short* bB[4];
#pragma unroll
  for (int g = 0; g < 4; ++g)
    bB[g] = WT + (size_t)(nbase + g * 16 + l15) * DM;

  const int klane = l4 * 8;  // per-lane k sub-offset (elements)

  f32x4 acc[2][4] = {};

#pragma unroll
  for (int t = 0; t < 16; ++t) {
    const int k0 = t * 64 + klane;
    float4 a32[2][2][2];   // [f][kk][half]
    bf16x8 bfv[4][2];
#pragma unroll
    for (int f = 0; f < 2; ++f)
#pragma unroll
      for (int kk = 0; kk < 2; ++kk) {
        const float* p = aA[f] + k0 + kk * 32;
        a32[f][kk][0] = *(const float4*)(p);
        a32[f][kk][1] = *(const float4*)(p + 4);
      }
#pragma unroll
    for (int g = 0; g < 4; ++g)
#pragma unroll
      for (int kk = 0; kk < 2; ++kk)
        bfv[g][kk] = *(const bf16x8*)(bB[g] + k0 + kk * 32);

    bf16x8 af[2][2];
#pragma unroll
    for (int f = 0; f < 2; ++f)
#pragma unroll
      for (int kk = 0; kk < 2; ++kk) {
        const float4 x = a32[f][kk][0], y = a32[f][kk][1];
        bf16x8 pk;
        pk[0] = (short)f2bf(x.x); pk[1] = (short)f2bf(x.y);
        pk[2] = (short)f2bf(x.z); pk[3] = (short)f2bf(x.w);
        pk[4] = (short)f2bf(y.x); pk[5] = (short)f2bf(y.y);
        pk[6] = (short)f2bf(y.z); pk[7] = (short)f2bf(y.w);
        af[f][kk] = pk;
      }
#pragma unroll
    for (int kk = 0; kk < 2; ++kk)
#pragma unroll
      for (int f = 0; f < 2; ++f)
#pragma unroll
        for (int g = 0; g < 4; ++g)
          acc[f][g] = __builtin_amdgcn_mfma_f32_16x16x32_bf16(
              af[f][kk], bfv[g][kk], acc[f][g], 0, 0, 0);
  }

  // epilogue: wave tile 32x64 at (Mtile*128 + w*32, nbase)
#pragma unroll
  for (int f = 0; f < 2; ++f) {
#pragma unroll
    for (int g = 0; g < 4; ++g) {
      const int mloc = w * 32 + f * 16 + l4 * 4;
      const int nloc = g * 16 + l15;
      const float bs = bias[nbase + nloc];
      if (mode == 2) {
        const int d = nbase - (bh & 7) * 128 + nloc;   // 0..127
        const int jp = Mtile * 128 + mloc;
        ushort4 o;
        o.x = f2bf(acc[f][g][0] + bs); o.y = f2bf(acc[f][g][1] + bs);
        o.z = f2bf(acc[f][g][2] + bs); o.w = f2bf(acc[f][g][3] + bs);
        *(ushort4*)(&VpT[((size_t)bh * HD + d) * JPH + jp]) = o;
      } else if (mode == 1) {
        const int d = nbase - (bh & 7) * 128 + nloc;
        for (int i = 0; i < 4; ++i) {
          int jp = Mtile * 128 + mloc + i;
          Kp[((size_t)bh * JPH + jp) * HD + d] = f2bf(acc[f][g][i] + bs);
        }
      } else {
        for (int i = 0; i < 4; ++i) {
          int mg = Mtile * 128 + mloc + i;
          int bb = mg >> 10, tt2 = mg & 1023;
          int ng = nbase + nloc;
          int h = ng >> 7, d = ng & 127;
          Qp[(((size_t)bb * NH + h) * TGT + tt2) * HD + d] =
              f2bf((acc[f][g][i] + bs) * 0.08838834764831845f);
        }
      }
    }
  }
}

// ---------------------------------------------------------------------------
// Flash attention per (b,h), sparse j = h + 8*j'. 1D grid 256 (XCD-swizzled
// so each XCD owns 2 bh's KV, L2-resident), 256 thr. KV double-buffered with
// counted prefetch: stage(jt+1) issued before compute, drained at iter bottom.
// ---------------------------------------------------------------------------
__global__ __launch_bounds__(256) void attn_kernel(
    const unsigned short* __restrict__ Qp, const unsigned short* __restrict__ Kp,
    const unsigned short* __restrict__ VpT, unsigned short* __restrict__ O) {
  __shared__ unsigned short Klds[2][64 * 128];  // 16 KB each, swizzled
  __shared__ unsigned short Vlds[2][128 * 64];  // 16 KB each, swizzled
  __shared__ unsigned short Plds[4 * 16 * 64];  // per-wave, 8 KB
  const int tid = threadIdx.x, lane = tid & 63, w = tid >> 6;
  const int bid = blockIdx.x;
  const int lbid = (bid & 7) * 32 + (bid >> 3);  // 256 = 8 * 32
  const int tq = lbid & 15, bh = lbid >> 4;
  const int T0 = tq * 64 + w * 16;
  const int l15 = lane & 15, l4 = lane >> 4;

  bf16x8 qf[4];
  {
    const unsigned short* qrow = &Qp[((size_t)bh * TGT + T0 + l15) * HD];
    for (int kf = 0; kf < 4; ++kf)
      qf[kf] = *(const bf16x8*)(&qrow[kf * 32 + l4 * 8]);
  }

  f32x4 acc_o[8] = {};
  float m_run = -INFINITY, l_run = 0.f;

  const unsigned short* kbh = Kp + (size_t)bh * JPH * HD;
  const unsigned short* vbh = VpT + (size_t)bh * HD * JPH;

  auto stage = [&](int jt, int buf) {
    const int j0 = jt * 64;
#pragma unroll
    for (int it = 0; it < 4; ++it) {
      int rb = w * 16 + it * 4;
      int row = rb + l4;
      const unsigned char* g =
          (const unsigned char*)(kbh + (size_t)(j0 + row) * HD);
      g += (l15 * 16) ^ ((row & 7) << 4);
      gload_lds16(g, &Klds[buf][rb * 128]);
    }
#pragma unroll
    for (int it = 0; it < 4; ++it) {
      int rb = w * 32 + it * 8;
      int d = rb + (lane >> 3);
      const unsigned char* g =
          (const unsigned char*)(vbh + (size_t)d * JPH + j0);
      g += ((lane & 7) * 16) ^ ((d & 7) << 4);
      gload_lds16(g, &Vlds[buf][rb * 64]);
    }
  };

  stage(0, 0);
  asm volatile("s_waitcnt vmcnt(0)" ::: "memory");
  __builtin_amdgcn_s_barrier();
  __builtin_amdgcn_sched_barrier(0);

  for (int jt = 0; jt < 16; ++jt) {
    const int cb = jt & 1;
    if (jt < 15) stage(jt + 1, cb ^ 1);

    f32x4 acc_s[4] = {};
    for (int jf = 0; jf < 4; ++jf) {
      const int j = jf * 16 + l15;
      for (int kf = 0; kf < 4; ++kf) {
        int byteoff = (j * 256 + (kf * 32 + l4 * 8) * 2) ^ ((j & 7) << 4);
        bf16x8 kfr = *(const bf16x8*)((const unsigned char*)Klds[cb] + byteoff);
        acc_s[jf] = __builtin_amdgcn_mfma_f32_16x16x32_bf16(
            kfr, qf[kf], acc_s[jf], 0, 0, 0);
      }
    }

    float pmax = -INFINITY;
    for (int jf = 0; jf < 4; ++jf)
      for (int i = 0; i < 4; ++i) pmax = fmaxf(pmax, acc_s[jf][i]);
    pmax = fmaxf(pmax, __shfl_xor(pmax, 16, 64));
    pmax = fmaxf(pmax, __shfl_xor(pmax, 32, 64));
    const float m_new = fmaxf(m_run, pmax);
    const float alpha = exp2f((m_run - m_new) * LOG2E);
    float psum = 0.f;
    for (int jf = 0; jf < 4; ++jf) {
      float p0 = exp2f((acc_s[jf][0] - m_new) * LOG2E);
      float p1 = exp2f((acc_s[jf][1] - m_new) * LOG2E);
      float p2 = exp2f((acc_s[jf][2] - m_new) * LOG2E);
      float p3 = exp2f((acc_s[jf][3] - m_new) * LOG2E);
      psum += (p0 + p1) + (p2 + p3);
      ushort4 pk;
      pk.x = f2bf(p0); pk.y = f2bf(p1); pk.z = f2bf(p2); pk.w = f2bf(p3);
      int byteoff = (w * 2048 + l15 * 128 + (jf * 16 + l4 * 4) * 2) ^ ((l15 & 7) << 4);
      *(ushort4*)((unsigned char*)Plds + byteoff) = pk;
    }
    psum += __shfl_xor(psum, 16, 64);
    psum += __shfl_xor(psum, 32, 64);
    l_run = l_run * alpha + psum;
    m_run = m_new;

    float alphar[4];
    for (int i = 0; i < 4; ++i)
      alphar[i] = __shfl(alpha, (lane & 48) | (l4 * 4 + i), 64);
    for (int df = 0; df < 8; ++df) {
      acc_o[df][0] *= alphar[0]; acc_o[df][1] *= alphar[1];
      acc_o[df][2] *= alphar[2]; acc_o[df][3] *= alphar[3];
    }

    for (int kf2 = 0; kf2 < 2; ++kf2) {
      int poff = (w * 2048 + l15 * 128 + (kf2 * 32 + l4 * 8) * 2) ^ ((l15 & 7) << 4);
      bf16x8 pf = *(const bf16x8*)((const unsigned char*)Plds + poff);
      for (int df = 0; df < 8; ++df) {
        int d = df * 16 + l15;
        int voff = (d * 128 + (kf2 * 32 + l4 * 8) * 2) ^ ((d & 7) << 4);
        bf16x8 vf = *(const bf16x8*)((const unsigned char*)Vlds[cb] + voff);
        acc_o[df] = __builtin_amdgcn_mfma_f32_16x16x32_bf16(
            pf, vf, acc_o[df], 0, 0, 0);
      }
    }

    asm volatile("s_waitcnt vmcnt(0)" ::: "memory");  // stage(jt+1) landed
    __builtin_amdgcn_s_barrier();
    __builtin_amdgcn_sched_barrier(0);
  }

  const float li = 1.0f / l_run;
  float linv[4];
  for (int i = 0; i < 4; ++i)
    linv[i] = __shfl(li, (lane & 48) | (l4 * 4 + i), 64);

  const int b = bh >> 3, h = bh & 7;
  for (int df = 0; df < 8; ++df)
    for (int i = 0; i < 4; ++i) {
      int t = T0 + l4 * 4 + i;
      int d = df * 16 + l15;
      O[((size_t)b * TGT + t) * DM + h * HD + d] = f2bf(acc_o[df][i] * linv[i]);
    }
}

// ---------------------------------------------------------------------------
// Output projection v2: BM=64, BN=128 -> grid (8 n, 32 m) = 256 blocks.
// Both operands gload_lds dbuf, 2-phase counted prefetch. LDS 48 KB.
// ---------------------------------------------------------------------------
__global__ __launch_bounds__(256) void oproj_kernel(
    const unsigned short* __restrict__ Oin, const unsigned short* __restrict__ WoT,
    const float* __restrict__ bo, float* __restrict__ out) {
  __shared__ unsigned short Ab[2][64 * 64];    // 8 KB each
  __shared__ unsigned short Bb[2][128 * 64];   // 16 KB each
  const int tid = threadIdx.x, lane = tid & 63, w = tid >> 6;
  const int wm = w >> 1, wn = w & 1;
  const int n0 = blockIdx.x * 128, m0 = blockIdx.y * 64;
  const int l15 = lane & 15, l4 = lane >> 4;

  auto stageA = [&](int t, int buf) {
    const int kk0 = t * 64;
#pragma unroll
    for (int it = 0; it < 2; ++it) {
      int gi = w * 2 + it;               // 8 groups of 8 rows
      int row = gi * 8 + (lane >> 3);
      const unsigned char* g =
          (const unsigned char*)&Oin[(size_t)(m0 + row) * DM + kk0];
      g += ((lane & 7) * 16) ^ ((row & 7) << 4);
      gload_lds16(g, (unsigned char*)Ab[buf] + gi * 1024);
    }
  };
  auto stageB = [&](int t, int buf) {
    const int kk0 = t * 64;
#pragma unroll
    for (int it = 0; it < 4; ++it) {
      int gi = w * 4 + it;               // 16 groups of 8 rows
      int row = gi * 8 + (lane >> 3);
      const unsigned char* g =
          (const unsigned char*)&WoT[(size_t)(n0 + row) * DM + kk0];
      g += ((lane & 7) * 16) ^ ((row & 7) << 4);
      gload_lds16(g, (unsigned char*)Bb[buf] + gi * 1024);
    }
  };

  f32x4 acc[2][4] = {};
  stageA(0, 0);
  stageB(0, 0);
  asm volatile("s_waitcnt vmcnt(0)" ::: "memory");
  __builtin_amdgcn_s_barrier();
  __builtin_amdgcn_sched_barrier(0);

  for (int t = 0; t < 16; ++t) {
    const int cur = t & 1;
    if (t < 15) { stageA(t + 1, cur ^ 1); stageB(t + 1, cur ^ 1); }

    bf16x8 af[2][2], bfr[4][2];
#pragma unroll
    for (int kk = 0; kk < 2; ++kk) {
#pragma unroll
      for (int f = 0; f < 2; ++f) {
        int ra = wm * 32 + f * 16 + l15;
        int ka = (kk * 64 + l4 * 16) ^ ((ra & 7) << 4);
        af[f][kk] = *(const bf16x8*)((const unsigned char*)Ab[cur] + ra * 128 + ka);
      }
#pragma unroll
      for (int g = 0; g < 4; ++g) {
        int rb = wn * 64 + g * 16 + l15;
        int kb = (kk * 64 + l4 * 16) ^ ((rb & 7) << 4);
        bfr[g][kk] = *(const bf16x8*)((const unsigned char*)Bb[cur] + rb * 128 + kb);
      }
    }
#pragma unroll
    for (int kk = 0; kk < 2; ++kk)
#pragma unroll
      for (int f = 0; f < 2; ++f)
#pragma unroll
        for (int g = 0; g < 4; ++g)
          acc[f][g] = __builtin_amdgcn_mfma_f32_16x16x32_bf16(
              af[f][kk], bfr[g][kk], acc[f][g], 0, 0, 0);

    asm volatile("s_waitcnt vmcnt(0) lgkmcnt(0)" ::: "memory");
    __builtin_amdgcn_s_barrier();
    __builtin_amdgcn_sched_barrier(0);
  }

#pragma unroll
  for (int f = 0; f < 2; ++f)
#pragma unroll
    for (int g = 0; g < 4; ++g) {
      int nn = n0 + wn * 64 + g * 16 + l15;
      float bs = bo[nn];
      for (int i = 0; i < 4; ++i) {
        int mm = m0 + wm * 32 + f * 16 + l4 * 4 + i;
        out[(size_t)mm * DM + nn] = acc[f][g][i] + bs;
      }
    }
}

// ---------------------------------------------------------------------------
extern "C" void kernel_launch(void* const* d_in, const int* in_sizes, int n_in,
                              void* d_out, int out_size, void* d_ws,
                              size_t ws_size, hipStream_t stream) {
  const float* q  = (const float*)d_in[0];
  const float* k  = (const float*)d_in[1];
  const float* v  = (const float*)d_in[2];
  const float* Wq = (const float*)d_in[3];
  const float* bq = (const float*)d_in[4];
  const float* Wk = (const float*)d_in[5];
  const float* bk = (const float*)d_in[6];
  const float* Wv = (const float*)d_in[7];
  const float* bv = (const float*)d_in[8];
  const float* Wo = (const float*)d_in[9];
  const float* bo = (const float*)d_in[10];
  float* out = (float*)d_out;

  unsigned short* WT  = (unsigned short*)d_ws;      // 4 x 1024x1024 bf16 (8 MB)
  unsigned short* Qp  = WT + (size_t)4 * DM * DM;   // [2][8][1024][128] (4 MB)
  unsigned short* Kp  = Qp + (size_t)2 * DM * DM;   // [16][1024][128]   (4 MB)
  unsigned short* VpT = Kp + (size_t)2 * DM * DM;   // [16][128][1024]   (4 MB)
  unsigned short* Obf = VpT + (size_t)2 * DM * DM;  // [2][1024][1024]   (4 MB)

  hipLaunchKernelGGL(wconv_kernel, dim3(16, 16, 4), dim3(256), 0, stream,
                     Wq, Wk, Wv, Wo, WT);
  hipLaunchKernelGGL(proj_fused_kernel, dim3(768), dim3(256), 0, stream,
                     q, k, v, WT, bq, bk, bv, Qp, Kp, VpT);
  hipLaunchKernelGGL(attn_kernel, dim3(256), dim3(256), 0, stream,
                     Qp, Kp, VpT, Obf);
  hipLaunchKernelGGL(oproj_kernel, dim3(8, 32), dim3(256), 0, stream,
                     Obf, WT + (size_t)3 * DM * DM, bo, out);
}

// Round 10
// 95.655 us; speedup vs baseline: 1.7703x; 1.7703x over previous
//
#include <hip/hip_runtime.h>
#include <hip/hip_bf16.h>
#include <stdint.h>

#define DM 1024
#define HD 128
#define NH 8
#define NB 2
#define TGT 1024
#define SRC 8192
#define JPH 1024
#define LOG2E 1.4426950408889634f

typedef __attribute__((ext_vector_type(8))) short bf16x8;
typedef __attribute__((ext_vector_type(4))) float f32x4;

__device__ __forceinline__ unsigned short f2bf(float f) {
  __hip_bfloat16 h = __float2bfloat16(f);
  return __builtin_bit_cast(unsigned short, h);
}

__device__ __forceinline__ void gload_lds16(const void* g, void* l) {
  __builtin_amdgcn_global_load_lds(
      (const __attribute__((address_space(1))) unsigned int*)g,
      (__attribute__((address_space(3))) unsigned int*)l, 16, 0, 0);
}

// ---------------------------------------------------------------------------
// Weight transpose + fp32->bf16 convert: WT[n][k] = bf16(W[k][n])
// ---------------------------------------------------------------------------
__global__ __launch_bounds__(256) void wconv_kernel(
    const float* __restrict__ Wq, const float* __restrict__ Wk,
    const float* __restrict__ Wv, const float* __restrict__ Wo,
    unsigned short* __restrict__ WTout) {
  __shared__ float tile[64][65];
  const float* W = (blockIdx.z == 0) ? Wq : (blockIdx.z == 1) ? Wk
                   : (blockIdx.z == 2) ? Wv : Wo;
  unsigned short* WT = WTout + (size_t)blockIdx.z * DM * DM;
  const int k0 = blockIdx.x * 64, n0 = blockIdx.y * 64;
  const int tid = threadIdx.x;
  const int tr = tid >> 4, tc = (tid & 15) * 4;
  for (int it = 0; it < 4; ++it) {
    int r = tr + it * 16;
    float4 vv = *(const float4*)(&W[(size_t)(k0 + r) * DM + n0 + tc]);
    tile[r][tc] = vv.x; tile[r][tc + 1] = vv.y;
    tile[r][tc + 2] = vv.z; tile[r][tc + 3] = vv.w;
  }
  __syncthreads();
  for (int it = 0; it < 4; ++it) {
    int n = tr + it * 16;
    ushort4 o;
    o.x = f2bf(tile[tc + 0][n]); o.y = f2bf(tile[tc + 1][n]);
    o.z = f2bf(tile[tc + 2][n]); o.w = f2bf(tile[tc + 3][n]);
    *(ushort4*)(&WT[(size_t)(n0 + n) * DM + k0 + tc]) = o;
  }
}

// ---------------------------------------------------------------------------
// Fused projection GEMM (round-6 v4 structure, best measured: 60 µs) +
// bijective XCD swizzle (768 = 8x96) for weight-panel L2 locality.
// BM=64, BN=128, BK=64, 4 waves (2M x 2N, 32x64/wave), 3 blocks/CU.
// T4 schedule: counted vmcnt + raw s_barrier; A reg-staged depth 2; B via
// gload_lds dbuf. LDS 48 KB.
//   lbid 0..255  : mode 0, Q -> Qp (scaled); Mtile=sub>>3 (0..31)
//   lbid 256..511: mode 1, K rows j=h+8j' -> Kp; bh=sub>>4, Mtile=sub&15
//   lbid 512..767: mode 2, V rows j=h+8j' -> VpT
// ---------------------------------------------------------------------------
__global__ __launch_bounds__(256, 3) void proj_fused_kernel(
    const float* __restrict__ q, const float* __restrict__ k,
    const float* __restrict__ v, const unsigned short* __restrict__ WTall,
    const float* __restrict__ bq, const float* __restrict__ bk,
    const float* __restrict__ bv, unsigned short* __restrict__ Qp,
    unsigned short* __restrict__ Kp, unsigned short* __restrict__ VpT) {
  __shared__ unsigned short Ab[2][64 * 64];    // 8 KB each, XOR-swizzled
  __shared__ unsigned short Bb[2][128 * 64];   // 16 KB each
  const int tid = threadIdx.x, lane = tid & 63, w = tid >> 6;
  const int wm = w >> 1, wn = w & 1;
  const int l15 = lane & 15, l4 = lane >> 4;

  // bijective XCD swizzle: 768 = 8 * 96
  const int bid = blockIdx.x;
  const int lbid = (bid & 7) * 96 + (bid >> 3);
  const int mode = lbid >> 8;
  const int sub = lbid & 255;
  const float* Asrc;
  const unsigned short* WT;
  const float* bias;
  int nbase, bh = 0, Mtile;
  if (mode == 0) {
    Asrc = q; WT = WTall; bias = bq;
    Mtile = sub >> 3; nbase = (sub & 7) * 128;
  } else {
    bh = sub >> 4; Mtile = sub & 15;
    nbase = (bh & 7) * 128;
    if (mode == 1) { Asrc = k; WT = WTall + (size_t)DM * DM; bias = bk; }
    else           { Asrc = v; WT = WTall + (size_t)2 * DM * DM; bias = bv; }
  }

  // A staging: one row per thread (ar=tid>>2, 0..63), 16 contiguous fp32
  const int ar = tid >> 2;
  const int ac = (tid & 3) * 16;       // fp32 col base
  size_t growA;
  if (mode == 0) growA = (size_t)(Mtile * 64 + ar);
  else growA = (size_t)(bh >> 3) * SRC + (size_t)(bh & 7) +
               8u * (size_t)(Mtile * 64 + ar);
  const float* aptr = &Asrc[growA * DM + ac];

  auto issueA = [&](int t, float4 (&R)[4]) {
    const float* src = aptr + t * 64;
#pragma unroll
    for (int i = 0; i < 4; ++i) R[i] = *(const float4*)(src + i * 4);
  };
  auto commitA = [&](float4 (&R)[4], int buf) {
    unsigned char* abase = (unsigned char*)Ab[buf] + ar * 128;
#pragma unroll
    for (int h = 0; h < 2; ++h) {
      bf16x8 pk;
      float4 x = R[h * 2], y = R[h * 2 + 1];
      pk[0] = (short)f2bf(x.x); pk[1] = (short)f2bf(x.y);
      pk[2] = (short)f2bf(x.z); pk[3] = (short)f2bf(x.w);
      pk[4] = (short)f2bf(y.x); pk[5] = (short)f2bf(y.y);
      pk[6] = (short)f2bf(y.z); pk[7] = (short)f2bf(y.w);
      int b0 = (ac * 2 + h * 16) ^ ((ar & 7) << 4);
      *(bf16x8*)(abase + b0) = pk;
    }
  };
  auto stageB = [&](int t, int buf) {
    const int kk0 = t * 64;
#pragma unroll
    for (int it = 0; it < 4; ++it) {
      int gi = w * 4 + it;              // 16 groups of 8 rows
      int row = gi * 8 + (lane >> 3);
      const unsigned char* g =
          (const unsigned char*)&WT[(size_t)(nbase + row) * DM + kk0];
      g += ((lane & 7) * 16) ^ ((row & 7) << 4);
      gload_lds16(g, (unsigned char*)Bb[buf] + gi * 1024);
    }
  };

  f32x4 acc[2][4] = {};
  float4 aR0[4], aR1[4];

  // prologue
  stageB(0, 0);
  issueA(0, aR0);
  issueA(1, aR1);
  commitA(aR0, 0);  // compiler waits for aR0 (retires B0 too)
  asm volatile("s_waitcnt vmcnt(4) lgkmcnt(0)" ::: "memory");
  __builtin_amdgcn_s_barrier();
  __builtin_amdgcn_sched_barrier(0);

  auto body = [&](int T, int CUR, float4 (&RC)[4], float4 (&RN)[4]) {
    if (T + 1 < 16) stageB(T + 1, CUR ^ 1);   // 4 gload_lds
    if (T + 2 < 16) issueA(T + 2, RC);        // 4 loads (reuse RC regs)

    bf16x8 af[2][2], bfr[4][2];
#pragma unroll
    for (int kk = 0; kk < 2; ++kk) {
#pragma unroll
      for (int f = 0; f < 2; ++f) {
        int ra = wm * 32 + f * 16 + l15;
        int ka = (kk * 64 + l4 * 16) ^ ((ra & 7) << 4);
        af[f][kk] = *(const bf16x8*)((const unsigned char*)Ab[CUR] + ra * 128 + ka);
      }
#pragma unroll
      for (int g = 0; g < 4; ++g) {
        int rb = wn * 64 + g * 16 + l15;
        int kb = (kk * 64 + l4 * 16) ^ ((rb & 7) << 4);
        bfr[g][kk] = *(const bf16x8*)((const unsigned char*)Bb[CUR] + rb * 128 + kb);
      }
    }
#pragma unroll
    for (int kk = 0; kk < 2; ++kk)
#pragma unroll
      for (int f = 0; f < 2; ++f)
#pragma unroll
        for (int g = 0; g < 4; ++g)
          acc[f][g] = __builtin_amdgcn_mfma_f32_16x16x32_bf16(
              af[f][kk], bfr[g][kk], acc[f][g], 0, 0, 0);

    if (T + 1 < 16) commitA(RN, CUR ^ 1);     // compiler waits RN regs

    if (T + 2 < 16)
      asm volatile("s_waitcnt vmcnt(4) lgkmcnt(0)" ::: "memory");  // keep A(T+2)
    else
      asm volatile("s_waitcnt vmcnt(0) lgkmcnt(0)" ::: "memory");  // tail drain
    __builtin_amdgcn_s_barrier();
    __builtin_amdgcn_sched_barrier(0);
  };

  for (int tt = 0; tt < 16; tt += 2) {
    body(tt, 0, aR0, aR1);
    body(tt + 1, 1, aR1, aR0);
  }

  // epilogue
#pragma unroll
  for (int f = 0; f < 2; ++f) {
#pragma unroll
    for (int g = 0; g < 4; ++g) {
      const int mloc = wm * 32 + f * 16 + l4 * 4;
      const int nloc = wn * 64 + g * 16 + l15;
      const float bs = bias[nbase + nloc];
      if (mode == 2) {
        const int d = nloc;
        const int jp = Mtile * 64 + mloc;
        ushort4 o;
        o.x = f2bf(acc[f][g][0] + bs); o.y = f2bf(acc[f][g][1] + bs);
        o.z = f2bf(acc[f][g][2] + bs); o.w = f2bf(acc[f][g][3] + bs);
        *(ushort4*)(&VpT[((size_t)bh * HD + d) * JPH + jp]) = o;
      } else if (mode == 1) {
        for (int i = 0; i < 4; ++i) {
          int jp = Mtile * 64 + mloc + i;
          Kp[((size_t)bh * JPH + jp) * HD + nloc] = f2bf(acc[f][g][i] + bs);
        }
      } else {
        for (int i = 0; i < 4; ++i) {
          int mg = Mtile * 64 + mloc + i;
          int bb = mg >> 10, tt2 = mg & 1023;
          int ng = nbase + nloc;
          int h = ng >> 7, d = ng & 127;
          Qp[(((size_t)bb * NH + h) * TGT + tt2) * HD + d] =
              f2bf((acc[f][g][i] + bs) * 0.08838834764831845f);
        }
      }
    }
  }
}

// ---------------------------------------------------------------------------
// Flash attention per (b,h), sparse j = h + 8*j'. 1D grid 256 (XCD-swizzled
// so each XCD owns 2 bh's KV, L2-resident), 256 thr. KV double-buffered with
// counted prefetch: stage(jt+1) issued before compute, drained at iter bottom.
// ---------------------------------------------------------------------------
__global__ __launch_bounds__(256) void attn_kernel(
    const unsigned short* __restrict__ Qp, const unsigned short* __restrict__ Kp,
    const unsigned short* __restrict__ VpT, unsigned short* __restrict__ O) {
  __shared__ unsigned short Klds[2][64 * 128];  // 16 KB each, swizzled
  __shared__ unsigned short Vlds[2][128 * 64];  // 16 KB each, swizzled
  __shared__ unsigned short Plds[4 * 16 * 64];  // per-wave, 8 KB
  const int tid = threadIdx.x, lane = tid & 63, w = tid >> 6;
  const int bid = blockIdx.x;
  const int lbid = (bid & 7) * 32 + (bid >> 3);  // 256 = 8 * 32
  const int tq = lbid & 15, bh = lbid >> 4;
  const int T0 = tq * 64 + w * 16;
  const int l15 = lane & 15, l4 = lane >> 4;

  bf16x8 qf[4];
  {
    const unsigned short* qrow = &Qp[((size_t)bh * TGT + T0 + l15) * HD];
    for (int kf = 0; kf < 4; ++kf)
      qf[kf] = *(const bf16x8*)(&qrow[kf * 32 + l4 * 8]);
  }

  f32x4 acc_o[8] = {};
  float m_run = -INFINITY, l_run = 0.f;

  const unsigned short* kbh = Kp + (size_t)bh * JPH * HD;
  const unsigned short* vbh = VpT + (size_t)bh * HD * JPH;

  auto stage = [&](int jt, int buf) {
    const int j0 = jt * 64;
#pragma unroll
    for (int it = 0; it < 4; ++it) {
      int rb = w * 16 + it * 4;
      int row = rb + l4;
      const unsigned char* g =
          (const unsigned char*)(kbh + (size_t)(j0 + row) * HD);
      g += (l15 * 16) ^ ((row & 7) << 4);
      gload_lds16(g, &Klds[buf][rb * 128]);
    }
#pragma unroll
    for (int it = 0; it < 4; ++it) {
      int rb = w * 32 + it * 8;
      int d = rb + (lane >> 3);
      const unsigned char* g =
          (const unsigned char*)(vbh + (size_t)d * JPH + j0);
      g += ((lane & 7) * 16) ^ ((d & 7) << 4);
      gload_lds16(g, &Vlds[buf][rb * 64]);
    }
  };

  stage(0, 0);
  asm volatile("s_waitcnt vmcnt(0)" ::: "memory");
  __builtin_amdgcn_s_barrier();
  __builtin_amdgcn_sched_barrier(0);

  for (int jt = 0; jt < 16; ++jt) {
    const int cb = jt & 1;
    if (jt < 15) stage(jt + 1, cb ^ 1);

    f32x4 acc_s[4] = {};
    for (int jf = 0; jf < 4; ++jf) {
      const int j = jf * 16 + l15;
      for (int kf = 0; kf < 4; ++kf) {
        int byteoff = (j * 256 + (kf * 32 + l4 * 8) * 2) ^ ((j & 7) << 4);
        bf16x8 kfr = *(const bf16x8*)((const unsigned char*)Klds[cb] + byteoff);
        acc_s[jf] = __builtin_amdgcn_mfma_f32_16x16x32_bf16(
            kfr, qf[kf], acc_s[jf], 0, 0, 0);
      }
    }

    float pmax = -INFINITY;
    for (int jf = 0; jf < 4; ++jf)
      for (int i = 0; i < 4; ++i) pmax = fmaxf(pmax, acc_s[jf][i]);
    pmax = fmaxf(pmax, __shfl_xor(pmax, 16, 64));
    pmax = fmaxf(pmax, __shfl_xor(pmax, 32, 64));
    const float m_new = fmaxf(m_run, pmax);
    const float alpha = exp2f((m_run - m_new) * LOG2E);
    float psum = 0.f;
    for (int jf = 0; jf < 4; ++jf) {
      float p0 = exp2f((acc_s[jf][0] - m_new) * LOG2E);
      float p1 = exp2f((acc_s[jf][1] - m_new) * LOG2E);
      float p2 = exp2f((acc_s[jf][2] - m_new) * LOG2E);
      float p3 = exp2f((acc_s[jf][3] - m_new) * LOG2E);
      psum += (p0 + p1) + (p2 + p3);
      ushort4 pk;
      pk.x = f2bf(p0); pk.y = f2bf(p1); pk.z = f2bf(p2); pk.w = f2bf(p3);
      int byteoff = (w * 2048 + l15 * 128 + (jf * 16 + l4 * 4) * 2) ^ ((l15 & 7) << 4);
      *(ushort4*)((unsigned char*)Plds + byteoff) = pk;
    }
    psum += __shfl_xor(psum, 16, 64);
    psum += __shfl_xor(psum, 32, 64);
    l_run = l_run * alpha + psum;
    m_run = m_new;

    float alphar[4];
    for (int i = 0; i < 4; ++i)
      alphar[i] = __shfl(alpha, (lane & 48) | (l4 * 4 + i), 64);
    for (int df = 0; df < 8; ++df) {
      acc_o[df][0] *= alphar[0]; acc_o[df][1] *= alphar[1];
      acc_o[df][2] *= alphar[2]; acc_o[df][3] *= alphar[3];
    }

    for (int kf2 = 0; kf2 < 2; ++kf2) {
      int poff = (w * 2048 + l15 * 128 + (kf2 * 32 + l4 * 8) * 2) ^ ((l15 & 7) << 4);
      bf16x8 pf = *(const bf16x8*)((const unsigned char*)Plds + poff);
      for (int df = 0; df < 8; ++df) {
        int d = df * 16 + l15;
        int voff = (d * 128 + (kf2 * 32 + l4 * 8) * 2) ^ ((d & 7) << 4);
        bf16x8 vf = *(const bf16x8*)((const unsigned char*)Vlds[cb] + voff);
        acc_o[df] = __builtin_amdgcn_mfma_f32_16x16x32_bf16(
            pf, vf, acc_o[df], 0, 0, 0);
      }
    }

    asm volatile("s_waitcnt vmcnt(0)" ::: "memory");  // stage(jt+1) landed
    __builtin_amdgcn_s_barrier();
    __builtin_amdgcn_sched_barrier(0);
  }

  const float li = 1.0f / l_run;
  float linv[4];
  for (int i = 0; i < 4; ++i)
    linv[i] = __shfl(li, (lane & 48) | (l4 * 4 + i), 64);

  const int b = bh >> 3, h = bh & 7;
  for (int df = 0; df < 8; ++df)
    for (int i = 0; i < 4; ++i) {
      int t = T0 + l4 * 4 + i;
      int d = df * 16 + l15;
      O[((size_t)b * TGT + t) * DM + h * HD + d] = f2bf(acc_o[df][i] * linv[i]);
    }
}

// ---------------------------------------------------------------------------
// Output projection v2: BM=64, BN=128 -> grid (8 n, 32 m) = 256 blocks.
// Both operands gload_lds dbuf, 2-phase counted prefetch. LDS 48 KB.
// ---------------------------------------------------------------------------
__global__ __launch_bounds__(256) void oproj_kernel(
    const unsigned short* __restrict__ Oin, const unsigned short* __restrict__ WoT,
    const float* __restrict__ bo, float* __restrict__ out) {
  __shared__ unsigned short Ab[2][64 * 64];    // 8 KB each
  __shared__ unsigned short Bb[2][128 * 64];   // 16 KB each
  const int tid = threadIdx.x, lane = tid & 63, w = tid >> 6;
  const int wm = w >> 1, wn = w & 1;
  const int n0 = blockIdx.x * 128, m0 = blockIdx.y * 64;
  const int l15 = lane & 15, l4 = lane >> 4;

  auto stageA = [&](int t, int buf) {
    const int kk0 = t * 64;
#pragma unroll
    for (int it = 0; it < 2; ++it) {
      int gi = w * 2 + it;               // 8 groups of 8 rows
      int row = gi * 8 + (lane >> 3);
      const unsigned char* g =
          (const unsigned char*)&Oin[(size_t)(m0 + row) * DM + kk0];
      g += ((lane & 7) * 16) ^ ((row & 7) << 4);
      gload_lds16(g, (unsigned char*)Ab[buf] + gi * 1024);
    }
  };
  auto stageB = [&](int t, int buf) {
    const int kk0 = t * 64;
#pragma unroll
    for (int it = 0; it < 4; ++it) {
      int gi = w * 4 + it;               // 16 groups of 8 rows
      int row = gi * 8 + (lane >> 3);
      const unsigned char* g =
          (const unsigned char*)&WoT[(size_t)(n0 + row) * DM + kk0];
      g += ((lane & 7) * 16) ^ ((row & 7) << 4);
      gload_lds16(g, (unsigned char*)Bb[buf] + gi * 1024);
    }
  };

  f32x4 acc[2][4] = {};
  stageA(0, 0);
  stageB(0, 0);
  asm volatile("s_waitcnt vmcnt(0)" ::: "memory");
  __builtin_amdgcn_s_barrier();
  __builtin_amdgcn_sched_barrier(0);

  for (int t = 0; t < 16; ++t) {
    const int cur = t & 1;
    if (t < 15) { stageA(t + 1, cur ^ 1); stageB(t + 1, cur ^ 1); }

    bf16x8 af[2][2], bfr[4][2];
#pragma unroll
    for (int kk = 0; kk < 2; ++kk) {
#pragma unroll
      for (int f = 0; f < 2; ++f) {
        int ra = wm * 32 + f * 16 + l15;
        int ka = (kk * 64 + l4 * 16) ^ ((ra & 7) << 4);
        af[f][kk] = *(const bf16x8*)((const unsigned char*)Ab[cur] + ra * 128 + ka);
      }
#pragma unroll
      for (int g = 0; g < 4; ++g) {
        int rb = wn * 64 + g * 16 + l15;
        int kb = (kk * 64 + l4 * 16) ^ ((rb & 7) << 4);
        bfr[g][kk] = *(const bf16x8*)((const unsigned char*)Bb[cur] + rb * 128 + kb);
      }
    }
#pragma unroll
    for (int kk = 0; kk < 2; ++kk)
#pragma unroll
      for (int f = 0; f < 2; ++f)
#pragma unroll
        for (int g = 0; g < 4; ++g)
          acc[f][g] = __builtin_amdgcn_mfma_f32_16x16x32_bf16(
              af[f][kk], bfr[g][kk], acc[f][g], 0, 0, 0);

    asm volatile("s_waitcnt vmcnt(0) lgkmcnt(0)" ::: "memory");
    __builtin_amdgcn_s_barrier();
    __builtin_amdgcn_sched_barrier(0);
  }

#pragma unroll
  for (int f = 0; f < 2; ++f)
#pragma unroll
    for (int g = 0; g < 4; ++g) {
      int nn = n0 + wn * 64 + g * 16 + l15;
      float bs = bo[nn];
      for (int i = 0; i < 4; ++i) {
        int mm = m0 + wm * 32 + f * 16 + l4 * 4 + i;
        out[(size_t)mm * DM + nn] = acc[f][g][i] + bs;
      }
    }
}

// ---------------------------------------------------------------------------
extern "C" void kernel_launch(void* const* d_in, const int* in_sizes, int n_in,
                              void* d_out, int out_size, void* d_ws,
                              size_t ws_size, hipStream_t stream) {
  const float* q  = (const float*)d_in[0];
  const float* k  = (const float*)d_in[1];
  const float* v  = (const float*)d_in[2];
  const float* Wq = (const float*)d_in[3];
  const float* bq = (const float*)d_in[4];
  const float* Wk = (const float*)d_in[5];
  const float* bk = (const float*)d_in[6];
  const float* Wv = (const float*)d_in[7];
  const float* bv = (const float*)d_in[8];
  const float* Wo = (const float*)d_in[9];
  const float* bo = (const float*)d_in[10];
  float* out = (float*)d_out;

  unsigned short* WT  = (unsigned short*)d_ws;      // 4 x 1024x1024 bf16 (8 MB)
  unsigned short* Qp  = WT + (size_t)4 * DM * DM;   // [2][8][1024][128] (4 MB)
  unsigned short* Kp  = Qp + (size_t)2 * DM * DM;   // [16][1024][128]   (4 MB)
  unsigned short* VpT = Kp + (size_t)2 * DM * DM;   // [16][128][1024]   (4 MB)
  unsigned short* Obf = VpT + (size_t)2 * DM * DM;  // [2][1024][1024]   (4 MB)

  hipLaunchKernelGGL(wconv_kernel, dim3(16, 16, 4), dim3(256), 0, stream,
                     Wq, Wk, Wv, Wo, WT);
  hipLaunchKernelGGL(proj_fused_kernel, dim3(768), dim3(256), 0, stream,
                     q, k, v, WT, bq, bk, bv, Qp, Kp, VpT);
  hipLaunchKernelGGL(attn_kernel, dim3(256), dim3(256), 0, stream,
                     Qp, Kp, VpT, Obf);
  hipLaunchKernelGGL(oproj_kernel, dim3(8, 32), dim3(256), 0, stream,
                     Obf, WT + (size_t)3 * DM * DM, bo, out);
}

// Round 11
// 92.582 us; speedup vs baseline: 1.8290x; 1.0332x over previous
//
#include <hip/hip_runtime.h>
#include <hip/hip_bf16.h>
#include <stdint.h>

#define DM 1024
#define HD 128
#define NH 8
#define NB 2
#define TGT 1024
#define SRC 8192
#define JPH 1024
#define LOG2E 1.4426950408889634f

typedef __attribute__((ext_vector_type(8))) short bf16x8;
typedef __attribute__((ext_vector_type(4))) float f32x4;

__device__ __forceinline__ unsigned short f2bf(float f) {
  __hip_bfloat16 h = __float2bfloat16(f);
  return __builtin_bit_cast(unsigned short, h);
}

__device__ __forceinline__ void gload_lds16(const void* g, void* l) {
  __builtin_amdgcn_global_load_lds(
      (const __attribute__((address_space(1))) unsigned int*)g,
      (__attribute__((address_space(3))) unsigned int*)l, 16, 0, 0);
}

// ---------------------------------------------------------------------------
// Weight transpose + fp32->bf16 convert: WT[n][k] = bf16(W[k][n])
// ---------------------------------------------------------------------------
__global__ __launch_bounds__(256) void wconv_kernel(
    const float* __restrict__ Wq, const float* __restrict__ Wk,
    const float* __restrict__ Wv, const float* __restrict__ Wo,
    unsigned short* __restrict__ WTout) {
  __shared__ float tile[64][65];
  const float* W = (blockIdx.z == 0) ? Wq : (blockIdx.z == 1) ? Wk
                   : (blockIdx.z == 2) ? Wv : Wo;
  unsigned short* WT = WTout + (size_t)blockIdx.z * DM * DM;
  const int k0 = blockIdx.x * 64, n0 = blockIdx.y * 64;
  const int tid = threadIdx.x;
  const int tr = tid >> 4, tc = (tid & 15) * 4;
  for (int it = 0; it < 4; ++it) {
    int r = tr + it * 16;
    float4 vv = *(const float4*)(&W[(size_t)(k0 + r) * DM + n0 + tc]);
    tile[r][tc] = vv.x; tile[r][tc + 1] = vv.y;
    tile[r][tc + 2] = vv.z; tile[r][tc + 3] = vv.w;
  }
  __syncthreads();
  for (int it = 0; it < 4; ++it) {
    int n = tr + it * 16;
    ushort4 o;
    o.x = f2bf(tile[tc + 0][n]); o.y = f2bf(tile[tc + 1][n]);
    o.z = f2bf(tile[tc + 2][n]); o.w = f2bf(tile[tc + 3][n]);
    *(ushort4*)(&WT[(size_t)(n0 + n) * DM + k0 + tc]) = o;
  }
}

// ---------------------------------------------------------------------------
// Fused projection GEMM (round-6 structure, best measured 60 µs).
// Identity block mapping (mode balance across XCDs — R10's grouped swizzle
// regressed via XCD load imbalance). Mode-0 index swap: Mtile=sub&31,
// nbase=(sub>>5)*128 so the 8 blocks sharing a q-panel are bids {m,m+32,...}
// == same XCD under default round-robin -> q panels L2-hit, balance kept.
// BM=64, BN=128, BK=64, 4 waves, 3 blocks/CU, T4 counted-vmcnt schedule.
// ---------------------------------------------------------------------------
__global__ __launch_bounds__(256, 3) void proj_fused_kernel(
    const float* __restrict__ q, const float* __restrict__ k,
    const float* __restrict__ v, const unsigned short* __restrict__ WTall,
    const float* __restrict__ bq, const float* __restrict__ bk,
    const float* __restrict__ bv, unsigned short* __restrict__ Qp,
    unsigned short* __restrict__ Kp, unsigned short* __restrict__ VpT) {
  __shared__ unsigned short Ab[2][64 * 64];    // 8 KB each, XOR-swizzled
  __shared__ unsigned short Bb[2][128 * 64];   // 16 KB each
  const int tid = threadIdx.x, lane = tid & 63, w = tid >> 6;
  const int wm = w >> 1, wn = w & 1;
  const int l15 = lane & 15, l4 = lane >> 4;

  const int lbid = blockIdx.x;   // identity: keeps mode mix balanced per XCD
  const int mode = lbid >> 8;
  const int sub = lbid & 255;
  const float* Asrc;
  const unsigned short* WT;
  const float* bias;
  int nbase, bh = 0, Mtile;
  if (mode == 0) {
    Asrc = q; WT = WTall; bias = bq;
    Mtile = sub & 31; nbase = (sub >> 5) * 128;   // panel-sharing -> same XCD
  } else {
    bh = sub >> 4; Mtile = sub & 15;
    nbase = (bh & 7) * 128;
    if (mode == 1) { Asrc = k; WT = WTall + (size_t)DM * DM; bias = bk; }
    else           { Asrc = v; WT = WTall + (size_t)2 * DM * DM; bias = bv; }
  }

  // A staging: one row per thread (ar=tid>>2, 0..63), 16 contiguous fp32
  const int ar = tid >> 2;
  const int ac = (tid & 3) * 16;       // fp32 col base
  size_t growA;
  if (mode == 0) growA = (size_t)(Mtile * 64 + ar);
  else growA = (size_t)(bh >> 3) * SRC + (size_t)(bh & 7) +
               8u * (size_t)(Mtile * 64 + ar);
  const float* aptr = &Asrc[growA * DM + ac];

  auto issueA = [&](int t, float4 (&R)[4]) {
    const float* src = aptr + t * 64;
#pragma unroll
    for (int i = 0; i < 4; ++i) R[i] = *(const float4*)(src + i * 4);
  };
  auto commitA = [&](float4 (&R)[4], int buf) {
    unsigned char* abase = (unsigned char*)Ab[buf] + ar * 128;
#pragma unroll
    for (int h = 0; h < 2; ++h) {
      bf16x8 pk;
      float4 x = R[h * 2], y = R[h * 2 + 1];
      pk[0] = (short)f2bf(x.x); pk[1] = (short)f2bf(x.y);
      pk[2] = (short)f2bf(x.z); pk[3] = (short)f2bf(x.w);
      pk[4] = (short)f2bf(y.x); pk[5] = (short)f2bf(y.y);
      pk[6] = (short)f2bf(y.z); pk[7] = (short)f2bf(y.w);
      int b0 = (ac * 2 + h * 16) ^ ((ar & 7) << 4);
      *(bf16x8*)(abase + b0) = pk;
    }
  };
  auto stageB = [&](int t, int buf) {
    const int kk0 = t * 64;
#pragma unroll
    for (int it = 0; it < 4; ++it) {
      int gi = w * 4 + it;              // 16 groups of 8 rows
      int row = gi * 8 + (lane >> 3);
      const unsigned char* g =
          (const unsigned char*)&WT[(size_t)(nbase + row) * DM + kk0];
      g += ((lane & 7) * 16) ^ ((row & 7) << 4);
      gload_lds16(g, (unsigned char*)Bb[buf] + gi * 1024);
    }
  };

  f32x4 acc[2][4] = {};
  float4 aR0[4], aR1[4];

  // prologue
  stageB(0, 0);
  issueA(0, aR0);
  issueA(1, aR1);
  commitA(aR0, 0);  // compiler waits for aR0 (retires B0 too)
  asm volatile("s_waitcnt vmcnt(4) lgkmcnt(0)" ::: "memory");
  __builtin_amdgcn_s_barrier();
  __builtin_amdgcn_sched_barrier(0);

  auto body = [&](int T, int CUR, float4 (&RC)[4], float4 (&RN)[4]) {
    if (T + 1 < 16) stageB(T + 1, CUR ^ 1);   // 4 gload_lds
    if (T + 2 < 16) issueA(T + 2, RC);        // 4 loads (reuse RC regs)

    bf16x8 af[2][2], bfr[4][2];
#pragma unroll
    for (int kk = 0; kk < 2; ++kk) {
#pragma unroll
      for (int f = 0; f < 2; ++f) {
        int ra = wm * 32 + f * 16 + l15;
        int ka = (kk * 64 + l4 * 16) ^ ((ra & 7) << 4);
        af[f][kk] = *(const bf16x8*)((const unsigned char*)Ab[CUR] + ra * 128 + ka);
      }
#pragma unroll
      for (int g = 0; g < 4; ++g) {
        int rb = wn * 64 + g * 16 + l15;
        int kb = (kk * 64 + l4 * 16) ^ ((rb & 7) << 4);
        bfr[g][kk] = *(const bf16x8*)((const unsigned char*)Bb[CUR] + rb * 128 + kb);
      }
    }
#pragma unroll
    for (int kk = 0; kk < 2; ++kk)
#pragma unroll
      for (int f = 0; f < 2; ++f)
#pragma unroll
        for (int g = 0; g < 4; ++g)
          acc[f][g] = __builtin_amdgcn_mfma_f32_16x16x32_bf16(
              af[f][kk], bfr[g][kk], acc[f][g], 0, 0, 0);

    if (T + 1 < 16) commitA(RN, CUR ^ 1);     // compiler waits RN regs

    if (T + 2 < 16)
      asm volatile("s_waitcnt vmcnt(4) lgkmcnt(0)" ::: "memory");  // keep A(T+2)
    else
      asm volatile("s_waitcnt vmcnt(0) lgkmcnt(0)" ::: "memory");  // tail drain
    __builtin_amdgcn_s_barrier();
    __builtin_amdgcn_sched_barrier(0);
  };

  for (int tt = 0; tt < 16; tt += 2) {
    body(tt, 0, aR0, aR1);
    body(tt + 1, 1, aR1, aR0);
  }

  // epilogue
#pragma unroll
  for (int f = 0; f < 2; ++f) {
#pragma unroll
    for (int g = 0; g < 4; ++g) {
      const int mloc = wm * 32 + f * 16 + l4 * 4;
      const int nloc = wn * 64 + g * 16 + l15;
      const float bs = bias[nbase + nloc];
      if (mode == 2) {
        const int d = nloc;
        const int jp = Mtile * 64 + mloc;
        ushort4 o;
        o.x = f2bf(acc[f][g][0] + bs); o.y = f2bf(acc[f][g][1] + bs);
        o.z = f2bf(acc[f][g][2] + bs); o.w = f2bf(acc[f][g][3] + bs);
        *(ushort4*)(&VpT[((size_t)bh * HD + d) * JPH + jp]) = o;
      } else if (mode == 1) {
        for (int i = 0; i < 4; ++i) {
          int jp = Mtile * 64 + mloc + i;
          Kp[((size_t)bh * JPH + jp) * HD + nloc] = f2bf(acc[f][g][i] + bs);
        }
      } else {
        for (int i = 0; i < 4; ++i) {
          int mg = Mtile * 64 + mloc + i;
          int bb = mg >> 10, tt2 = mg & 1023;
          int ng = nbase + nloc;
          int h = ng >> 7, d = ng & 127;
          Qp[(((size_t)bb * NH + h) * TGT + tt2) * HD + d] =
              f2bf((acc[f][g][i] + bs) * 0.08838834764831845f);
        }
      }
    }
  }
}

// ---------------------------------------------------------------------------
// Flash attention per (b,h), sparse j = h + 8*j'. 1D grid 256 (XCD-swizzled
// so each XCD owns 2 bh's KV, L2-resident), 256 thr. KV double-buffered with
// counted prefetch: stage(jt+1) issued before compute, drained at iter bottom.
// ---------------------------------------------------------------------------
__global__ __launch_bounds__(256) void attn_kernel(
    const unsigned short* __restrict__ Qp, const unsigned short* __restrict__ Kp,
    const unsigned short* __restrict__ VpT, unsigned short* __restrict__ O) {
  __shared__ unsigned short Klds[2][64 * 128];  // 16 KB each, swizzled
  __shared__ unsigned short Vlds[2][128 * 64];  // 16 KB each, swizzled
  __shared__ unsigned short Plds[4 * 16 * 64];  // per-wave, 8 KB
  const int tid = threadIdx.x, lane = tid & 63, w = tid >> 6;
  const int bid = blockIdx.x;
  const int lbid = (bid & 7) * 32 + (bid >> 3);  // 256 = 8 * 32
  const int tq = lbid & 15, bh = lbid >> 4;
  const int T0 = tq * 64 + w * 16;
  const int l15 = lane & 15, l4 = lane >> 4;

  bf16x8 qf[4];
  {
    const unsigned short* qrow = &Qp[((size_t)bh * TGT + T0 + l15) * HD];
    for (int kf = 0; kf < 4; ++kf)
      qf[kf] = *(const bf16x8*)(&qrow[kf * 32 + l4 * 8]);
  }

  f32x4 acc_o[8] = {};
  float m_run = -INFINITY, l_run = 0.f;

  const unsigned short* kbh = Kp + (size_t)bh * JPH * HD;
  const unsigned short* vbh = VpT + (size_t)bh * HD * JPH;

  auto stage = [&](int jt, int buf) {
    const int j0 = jt * 64;
#pragma unroll
    for (int it = 0; it < 4; ++it) {
      int rb = w * 16 + it * 4;
      int row = rb + l4;
      const unsigned char* g =
          (const unsigned char*)(kbh + (size_t)(j0 + row) * HD);
      g += (l15 * 16) ^ ((row & 7) << 4);
      gload_lds16(g, &Klds[buf][rb * 128]);
    }
#pragma unroll
    for (int it = 0; it < 4; ++it) {
      int rb = w * 32 + it * 8;
      int d = rb + (lane >> 3);
      const unsigned char* g =
          (const unsigned char*)(vbh + (size_t)d * JPH + j0);
      g += ((lane & 7) * 16) ^ ((d & 7) << 4);
      gload_lds16(g, &Vlds[buf][rb * 64]);
    }
  };

  stage(0, 0);
  asm volatile("s_waitcnt vmcnt(0)" ::: "memory");
  __builtin_amdgcn_s_barrier();
  __builtin_amdgcn_sched_barrier(0);

  for (int jt = 0; jt < 16; ++jt) {
    const int cb = jt & 1;
    if (jt < 15) stage(jt + 1, cb ^ 1);

    f32x4 acc_s[4] = {};
    for (int jf = 0; jf < 4; ++jf) {
      const int j = jf * 16 + l15;
      for (int kf = 0; kf < 4; ++kf) {
        int byteoff = (j * 256 + (kf * 32 + l4 * 8) * 2) ^ ((j & 7) << 4);
        bf16x8 kfr = *(const bf16x8*)((const unsigned char*)Klds[cb] + byteoff);
        acc_s[jf] = __builtin_amdgcn_mfma_f32_16x16x32_bf16(
            kfr, qf[kf], acc_s[jf], 0, 0, 0);
      }
    }

    float pmax = -INFINITY;
    for (int jf = 0; jf < 4; ++jf)
      for (int i = 0; i < 4; ++i) pmax = fmaxf(pmax, acc_s[jf][i]);
    pmax = fmaxf(pmax, __shfl_xor(pmax, 16, 64));
    pmax = fmaxf(pmax, __shfl_xor(pmax, 32, 64));
    const float m_new = fmaxf(m_run, pmax);
    const float alpha = exp2f((m_run - m_new) * LOG2E);
    float psum = 0.f;
    for (int jf = 0; jf < 4; ++jf) {
      float p0 = exp2f((acc_s[jf][0] - m_new) * LOG2E);
      float p1 = exp2f((acc_s[jf][1] - m_new) * LOG2E);
      float p2 = exp2f((acc_s[jf][2] - m_new) * LOG2E);
      float p3 = exp2f((acc_s[jf][3] - m_new) * LOG2E);
      psum += (p0 + p1) + (p2 + p3);
      ushort4 pk;
      pk.x = f2bf(p0); pk.y = f2bf(p1); pk.z = f2bf(p2); pk.w = f2bf(p3);
      int byteoff = (w * 2048 + l15 * 128 + (jf * 16 + l4 * 4) * 2) ^ ((l15 & 7) << 4);
      *(ushort4*)((unsigned char*)Plds + byteoff) = pk;
    }
    psum += __shfl_xor(psum, 16, 64);
    psum += __shfl_xor(psum, 32, 64);
    l_run = l_run * alpha + psum;
    m_run = m_new;

    float alphar[4];
    for (int i = 0; i < 4; ++i)
      alphar[i] = __shfl(alpha, (lane & 48) | (l4 * 4 + i), 64);
    for (int df = 0; df < 8; ++df) {
      acc_o[df][0] *= alphar[0]; acc_o[df][1] *= alphar[1];
      acc_o[df][2] *= alphar[2]; acc_o[df][3] *= alphar[3];
    }

    for (int kf2 = 0; kf2 < 2; ++kf2) {
      int poff = (w * 2048 + l15 * 128 + (kf2 * 32 + l4 * 8) * 2) ^ ((l15 & 7) << 4);
      bf16x8 pf = *(const bf16x8*)((const unsigned char*)Plds + poff);
      for (int df = 0; df < 8; ++df) {
        int d = df * 16 + l15;
        int voff = (d * 128 + (kf2 * 32 + l4 * 8) * 2) ^ ((d & 7) << 4);
        bf16x8 vf = *(const bf16x8*)((const unsigned char*)Vlds[cb] + voff);
        acc_o[df] = __builtin_amdgcn_mfma_f32_16x16x32_bf16(
            pf, vf, acc_o[df], 0, 0, 0);
      }
    }

    asm volatile("s_waitcnt vmcnt(0)" ::: "memory");  // stage(jt+1) landed
    __builtin_amdgcn_s_barrier();
    __builtin_amdgcn_sched_barrier(0);
  }

  const float li = 1.0f / l_run;
  float linv[4];
  for (int i = 0; i < 4; ++i)
    linv[i] = __shfl(li, (lane & 48) | (l4 * 4 + i), 64);

  const int b = bh >> 3, h = bh & 7;
  for (int df = 0; df < 8; ++df)
    for (int i = 0; i < 4; ++i) {
      int t = T0 + l4 * 4 + i;
      int d = df * 16 + l15;
      O[((size_t)b * TGT + t) * DM + h * HD + d] = f2bf(acc_o[df][i] * linv[i]);
    }
}

// ---------------------------------------------------------------------------
// Output projection v2: BM=64, BN=128 -> grid (8 n, 32 m) = 256 blocks.
// Both operands gload_lds dbuf, 2-phase counted prefetch. LDS 48 KB.
// ---------------------------------------------------------------------------
__global__ __launch_bounds__(256) void oproj_kernel(
    const unsigned short* __restrict__ Oin, const unsigned short* __restrict__ WoT,
    const float* __restrict__ bo, float* __restrict__ out) {
  __shared__ unsigned short Ab[2][64 * 64];    // 8 KB each
  __shared__ unsigned short Bb[2][128 * 64];   // 16 KB each
  const int tid = threadIdx.x, lane = tid & 63, w = tid >> 6;
  const int wm = w >> 1, wn = w & 1;
  const int n0 = blockIdx.x * 128, m0 = blockIdx.y * 64;
  const int l15 = lane & 15, l4 = lane >> 4;

  auto stageA = [&](int t, int buf) {
    const int kk0 = t * 64;
#pragma unroll
    for (int it = 0; it < 2; ++it) {
      int gi = w * 2 + it;               // 8 groups of 8 rows
      int row = gi * 8 + (lane >> 3);
      const unsigned char* g =
          (const unsigned char*)&Oin[(size_t)(m0 + row) * DM + kk0];
      g += ((lane & 7) * 16) ^ ((row & 7) << 4);
      gload_lds16(g, (unsigned char*)Ab[buf] + gi * 1024);
    }
  };
  auto stageB = [&](int t, int buf) {
    const int kk0 = t * 64;
#pragma unroll
    for (int it = 0; it < 4; ++it) {
      int gi = w * 4 + it;               // 16 groups of 8 rows
      int row = gi * 8 + (lane >> 3);
      const unsigned char* g =
          (const unsigned char*)&WoT[(size_t)(n0 + row) * DM + kk0];
      g += ((lane & 7) * 16) ^ ((row & 7) << 4);
      gload_lds16(g, (unsigned char*)Bb[buf] + gi * 1024);
    }
  };

  f32x4 acc[2][4] = {};
  stageA(0, 0);
  stageB(0, 0);
  asm volatile("s_waitcnt vmcnt(0)" ::: "memory");
  __builtin_amdgcn_s_barrier();
  __builtin_amdgcn_sched_barrier(0);

  for (int t = 0; t < 16; ++t) {
    const int cur = t & 1;
    if (t < 15) { stageA(t + 1, cur ^ 1); stageB(t + 1, cur ^ 1); }

    bf16x8 af[2][2], bfr[4][2];
#pragma unroll
    for (int kk = 0; kk < 2; ++kk) {
#pragma unroll
      for (int f = 0; f < 2; ++f) {
        int ra = wm * 32 + f * 16 + l15;
        int ka = (kk * 64 + l4 * 16) ^ ((ra & 7) << 4);
        af[f][kk] = *(const bf16x8*)((const unsigned char*)Ab[cur] + ra * 128 + ka);
      }
#pragma unroll
      for (int g = 0; g < 4; ++g) {
        int rb = wn * 64 + g * 16 + l15;
        int kb = (kk * 64 + l4 * 16) ^ ((rb & 7) << 4);
        bfr[g][kk] = *(const bf16x8*)((const unsigned char*)Bb[cur] + rb * 128 + kb);
      }
    }
#pragma unroll
    for (int kk = 0; kk < 2; ++kk)
#pragma unroll
      for (int f = 0; f < 2; ++f)
#pragma unroll
        for (int g = 0; g < 4; ++g)
          acc[f][g] = __builtin_amdgcn_mfma_f32_16x16x32_bf16(
              af[f][kk], bfr[g][kk], acc[f][g], 0, 0, 0);

    asm volatile("s_waitcnt vmcnt(0) lgkmcnt(0)" ::: "memory");
    __builtin_amdgcn_s_barrier();
    __builtin_amdgcn_sched_barrier(0);
  }

#pragma unroll
  for (int f = 0; f < 2; ++f)
#pragma unroll
    for (int g = 0; g < 4; ++g) {
      int nn = n0 + wn * 64 + g * 16 + l15;
      float bs = bo[nn];
      for (int i = 0; i < 4; ++i) {
        int mm = m0 + wm * 32 + f * 16 + l4 * 4 + i;
        out[(size_t)mm * DM + nn] = acc[f][g][i] + bs;
      }
    }
}

// ---------------------------------------------------------------------------
extern "C" void kernel_launch(void* const* d_in, const int* in_sizes, int n_in,
                              void* d_out, int out_size, void* d_ws,
                              size_t ws_size, hipStream_t stream) {
  const float* q  = (const float*)d_in[0];
  const float* k  = (const float*)d_in[1];
  const float* v  = (const float*)d_in[2];
  const float* Wq = (const float*)d_in[3];
  const float* bq = (const float*)d_in[4];
  const float* Wk = (const float*)d_in[5];
  const float* bk = (const float*)d_in[6];
  const float* Wv = (const float*)d_in[7];
  const float* bv = (const float*)d_in[8];
  const float* Wo = (const float*)d_in[9];
  const float* bo = (const float*)d_in[10];
  float* out = (float*)d_out;

  unsigned short* WT  = (unsigned short*)d_ws;      // 4 x 1024x1024 bf16 (8 MB)
  unsigned short* Qp  = WT + (size_t)4 * DM * DM;   // [2][8][1024][128] (4 MB)
  unsigned short* Kp  = Qp + (size_t)2 * DM * DM;   // [16][1024][128]   (4 MB)
  unsigned short* VpT = Kp + (size_t)2 * DM * DM;   // [16][128][1024]   (4 MB)
  unsigned short* Obf = VpT + (size_t)2 * DM * DM;  // [2][1024][1024]   (4 MB)

  hipLaunchKernelGGL(wconv_kernel, dim3(16, 16, 4), dim3(256), 0, stream,
                     Wq, Wk, Wv, Wo, WT);
  hipLaunchKernelGGL(proj_fused_kernel, dim3(768), dim3(256), 0, stream,
                     q, k, v, WT, bq, bk, bv, Qp, Kp, VpT);
  hipLaunchKernelGGL(attn_kernel, dim3(256), dim3(256), 0, stream,
                     Qp, Kp, VpT, Obf);
  hipLaunchKernelGGL(oproj_kernel, dim3(8, 32), dim3(256), 0, stream,
                     Obf, WT + (size_t)3 * DM * DM, bo, out);
}